// Round 7
// baseline (159.850 us; speedup 1.0000x reference)
//
#include <hip/hip_runtime.h>
#include <hip/hip_bf16.h>

// Attention block: qkv = x@Wqkv+b; MHA softmax; wavg; out = wavg@Wproj+b.
// B=8, P=1024, D=768, H=12, HD=64. Outputs: [out (8,1024,768), wavg (8,1024,768)] fp32.

typedef __attribute__((ext_vector_type(8))) short short8;
typedef __attribute__((ext_vector_type(4))) float f32x4;

#define MFMA_BF16(a, b, c) __builtin_amdgcn_mfma_f32_16x16x32_bf16((a), (b), (c), 0, 0, 0)

#define NB 8
#define NP 1024
#define ND 768
#define NH 12
#define NHD 64
#define NTOK (NB * NP)         // 8192
#define N3D (3 * ND)           // 2304
#define OUT_HALF (NTOK * ND)   // 6291456
// softmax scale (1/sqrt(64)) * log2(e), folded into Q so P = exp2(S)
#define QSCALE 0.18033688f

__device__ __forceinline__ void gload_lds16(const void* gptr, void* ldsptr) {
  __builtin_amdgcn_global_load_lds(
      (const __attribute__((address_space(1))) unsigned int*)gptr,
      (__attribute__((address_space(3))) unsigned int*)ldsptr, 16, 0, 0);
}

__device__ __forceinline__ unsigned pack_bf16x2(float a, float b) {
  __hip_bfloat162 h = __float22bfloat162_rn(float2{a, b});  // v_cvt_pk_bf16_f32
  return *reinterpret_cast<unsigned*>(&h);                  // a in low 16 bits
}

// GEMM-tile LDS swizzle ([rows][64 B] tiles); involution, XORs byte bits [6:4]
// with [9:7] -> per 16-consecutive-row ds_read_b128 group each bank class is
// hit exactly 2x (free). 16-B-granule preserving; row-period 16 so it works
// for 128-row and 256-row tiles alike. Verified r6: conflicts 3.5M -> 0.
__device__ __forceinline__ int swz_g(int b) { return b ^ (((b >> 7) & 7) << 4); }

// ---------------- conversion kernels ----------------

__global__ void k_cvt_x(const float* __restrict__ in, __hip_bfloat16* __restrict__ out) {
  int i = (blockIdx.x * 256 + threadIdx.x) * 8;
  float4 a = *(const float4*)(in + i);
  float4 b = *(const float4*)(in + i + 4);
  union { __hip_bfloat16 h[8]; uint4 u; } r;
  r.h[0] = __float2bfloat16(a.x); r.h[1] = __float2bfloat16(a.y);
  r.h[2] = __float2bfloat16(a.z); r.h[3] = __float2bfloat16(a.w);
  r.h[4] = __float2bfloat16(b.x); r.h[5] = __float2bfloat16(b.y);
  r.h[6] = __float2bfloat16(b.z); r.h[7] = __float2bfloat16(b.w);
  *(uint4*)(out + i) = r.u;
}

// in: [K][N] fp32 row-major -> out: [N][K] bf16 row-major (LDS-tiled transpose)
__global__ void k_cvt_t(const float* __restrict__ in, __hip_bfloat16* __restrict__ out,
                        int K, int N) {
  __shared__ float tile[32][33];
  int k0 = blockIdx.x * 32;
  int n0 = blockIdx.y * 32;
  int r = threadIdx.x >> 5;   // 0..7
  int c = threadIdx.x & 31;   // 0..31
#pragma unroll
  for (int i = 0; i < 4; ++i)
    tile[r + 8 * i][c] = in[(size_t)(k0 + r + 8 * i) * N + n0 + c];
  __syncthreads();
#pragma unroll
  for (int i = 0; i < 4; ++i)
    out[(size_t)(n0 + r + 8 * i) * K + k0 + c] = __float2bfloat16(tile[c][r + 8 * i]);
}

// ---------------- shared GEMM mainloop (128M x 256N tile) ----------------
// 4 waves; per-wave output 128x64 (acc[8][4]): 32 MFMA + 12 ds_read_b128 per
// BK=32 step (2x intensity of the old 128^2). 3 LDS buffers of 24 KB
// (A 128x32 = 8 KB + B 256x32 = 16 KB), depth-2 prefetch, COUNTED vmcnt(6)
// (6 loads/tile/thread: 2 A + 4 B; 2 tiles in flight = 12). Same verified
// sync structure as r4; swizzled via swz_g (rule 21).

__device__ __forceinline__ void gemm_mainloop(const __hip_bfloat16* __restrict__ A,
                                              const __hip_bfloat16* __restrict__ BT,
                                              int m0, int n0, char* Ls,
                                              f32x4 acc[8][4]) {
  const int tid = threadIdx.x;
  const int wid = tid >> 6, lane = tid & 63;   // wid = wn (N-split only)
  const int lrow = lane & 15, lk = lane >> 4;
  constexpr int K = 768, NKT = K / 32;   // 24 K-steps

  // swizzled, loop-invariant fragment read offsets
  int aoff[8], boff[4];
#pragma unroll
  for (int i = 0; i < 8; ++i)
    aoff[i] = swz_g((i * 16 + lrow) * 64 + lk * 16);
#pragma unroll
  for (int j = 0; j < 4; ++j)
    boff[j] = swz_g((wid * 64 + j * 16 + lrow) * 64 + lk * 16);

#define STAGE_G(kt, bi)                                                     \
  {                                                                         \
    const int k0s = (kt) * 32;                                              \
    char* dst = Ls + (bi) * 24576;                                          \
    _Pragma("unroll")                                                       \
    for (int t = 0; t < 2; ++t) {       /* A: 8 KB */                       \
      const int L = t * 4096 + tid * 16;                                    \
      const int lb = swz_g(L);                                              \
      gload_lds16(A + (size_t)(m0 + (lb >> 6)) * K + k0s + ((lb & 63) >> 1),\
                  dst + L);                                                 \
    }                                                                       \
    _Pragma("unroll")                                                       \
    for (int t = 0; t < 4; ++t) {       /* B: 16 KB */                      \
      const int L = t * 4096 + tid * 16;                                    \
      const int lb = swz_g(L);                                              \
      gload_lds16(BT + (size_t)(n0 + (lb >> 6)) * K + k0s + ((lb & 63) >> 1),\
                  dst + 8192 + L);                                          \
    }                                                                       \
  }

#define COMPUTE_T(kt)                                                       \
  {                                                                         \
    const char* buf = Ls + ((kt) % 3) * 24576;                              \
    short8 bfr[4];                                                          \
    _Pragma("unroll")                                                       \
    for (int j = 0; j < 4; ++j)                                             \
      bfr[j] = *(const short8*)(buf + 8192 + boff[j]);                      \
    _Pragma("unroll")                                                       \
    for (int i = 0; i < 8; ++i) {                                           \
      short8 afr = *(const short8*)(buf + aoff[i]);                         \
      _Pragma("unroll")                                                     \
      for (int j = 0; j < 4; ++j)                                           \
        acc[i][j] = MFMA_BF16(afr, bfr[j], acc[i][j]);                      \
    }                                                                       \
  }

  STAGE_G(0, 0);
  STAGE_G(1, 1);            // 12 loads/thread outstanding

#pragma unroll 3
  for (int kt = 0; kt < NKT - 1; ++kt) {
    // oldest 6 loads (= tile kt) done; tile kt+1 stays in flight
    asm volatile("s_waitcnt vmcnt(6)" ::: "memory");
    __builtin_amdgcn_s_barrier();
    if (kt + 2 < NKT) STAGE_G(kt + 2, (kt + 2) % 3);
    COMPUTE_T(kt);
  }
  // peeled last iteration: full drain
  asm volatile("s_waitcnt vmcnt(0)" ::: "memory");
  __builtin_amdgcn_s_barrier();
  COMPUTE_T(NKT - 1);

#undef STAGE_G
#undef COMPUTE_T
}

// ---------------- QKV GEMM: C[8192][2304] = x@Wqkv + b; scatter to q/k/vT ----------------
// grid 576 = 64 mt x 9 nt (logical wg = nt*64 + mt), XCD-chunk swizzled.

__launch_bounds__(256, 2)
__global__ void k_qkv_gemm(const __hip_bfloat16* __restrict__ A,
                           const __hip_bfloat16* __restrict__ BT,
                           const float* __restrict__ bias,
                           __hip_bfloat16* __restrict__ q_ws,   // [96][1024][64], pre-scaled
                           __hip_bfloat16* __restrict__ k_ws,   // [96][1024][64]
                           __hip_bfloat16* __restrict__ v_ws) { // [96][64][1024] (V^T)
  __shared__ char Ls[3 * 24576];
  const int wg = (blockIdx.x & 7) * 72 + (blockIdx.x >> 3);  // 576 % 8 == 0, bijective
  const int mt = wg & 63, nt = wg >> 6;
  const int m0 = mt * 128, n0 = nt * 256;
  const int wid = threadIdx.x >> 6, lane = threadIdx.x & 63;
  const int lrow = lane & 15, lk = lane >> 4;

  f32x4 acc[8][4] = {};
  gemm_mainloop(A, BT, m0, n0, Ls, acc);

  // each 256-wide N-tile lies entirely within q, k, or v (768 % 256 == 0)
  const int which = n0 / ND;
#pragma unroll
  for (int j = 0; j < 4; ++j) {
    const int n = n0 + wid * 64 + j * 16 + lrow;
    const float bv = bias[n];
    const int hh = (n % ND) >> 6;
    const int hd = n & 63;
#pragma unroll
    for (int i = 0; i < 8; ++i) {
      const int mbase = m0 + i * 16 + lk * 4;
#pragma unroll
      for (int r = 0; r < 4; ++r) {
        const int m = mbase + r;
        const float v = acc[i][j][r] + bv;
        const int b = m >> 10, p = m & 1023;
        const int bh = b * NH + hh;
        if (which == 0)      q_ws[((size_t)bh * NP + p) * NHD + hd] = __float2bfloat16(v * QSCALE);
        else if (which == 1) k_ws[((size_t)bh * NP + p) * NHD + hd] = __float2bfloat16(v);
        else                 v_ws[((size_t)bh * NHD + hd) * NP + p] = __float2bfloat16(v);
      }
    }
  }
}

// ---------------- attention ----------------
// 1 block = (bh, 64 q-rows), 4 waves x 16 q-rows. K/V chunks (64 keys) staged in
// LDS via global_load_lds, double-buffered, XOR-swizzled (rule 21).
// QK^T is SWAPPED: S^T = mfma(K_frag, Q_frag) so each lane holds P for one q-row
// (q = lrow) and 4 consecutive keys per 16-key tile -> cvt_pk pairs + b64 LDS
// writes at identity key layout; PV A-frag read is unchanged.

#define KVBLK 64

__launch_bounds__(256)
__global__ void k_attn(const __hip_bfloat16* __restrict__ q_ws,
                       const __hip_bfloat16* __restrict__ k_ws,
                       const __hip_bfloat16* __restrict__ v_ws,  // [bh][64][1024]
                       float* __restrict__ wavg_f32,             // [8][1024][768]
                       __hip_bfloat16* __restrict__ wavg_bf) {
  // buf: [2][ K(64x64 bf16 = 8KB) + V^T(64x64 bf16 = 8KB) ] + per-wave pbuf
  __shared__ char smem[2 * 16384 + 4 * 2304];
  const int bh = blockIdx.y;
  const int tid = threadIdx.x;
  const int wid = tid >> 6, lane = tid & 63;
  const int lrow = lane & 15, lk = lane >> 4;
  const int q0 = blockIdx.x * 64 + wid * 16;
  char* pbuf = smem + 32768 + wid * 2304;   // 16 rows x 144 B

  const __hip_bfloat16* Qb = q_ws + (size_t)bh * NP * NHD;
  const __hip_bfloat16* Kb = k_ws + (size_t)bh * NP * NHD;
  const __hip_bfloat16* Vb = v_ws + (size_t)bh * NHD * NP;

  // Q fragments (pre-scaled by QSCALE at QKV epilogue)
  short8 qf0 = *(const short8*)(Qb + (size_t)(q0 + lrow) * NHD + lk * 8);
  short8 qf1 = *(const short8*)(Qb + (size_t)(q0 + lrow) * NHD + 32 + lk * 8);

  f32x4 acc[4] = {};          // [hd-tile] 16 q x 16 hd each
  float dsa = 0.f, dsb = 0.f; // per-lane partial denom for q = lrow (own lk keys)

  // stage one 64-key chunk: K rows (stride 64 elem) + V^T rows (stride 1024 elem)
  // LDS linear dest; global src address carries the inverse swizzle.
#define STAGE(buf, key0)                                                          \
  {                                                                               \
    _Pragma("unroll")                                                             \
    for (int p = 0; p < 2; ++p) {                                                 \
      const int L = p * 4096 + tid * 16;                                          \
      const int r = L >> 7;                                                       \
      const int cb = L & 127;                                                     \
      const int sc = (cb ^ ((r & 7) << 4)) >> 1;  /* swizzled element col */      \
      gload_lds16(Kb + (size_t)((key0) + r) * NHD + sc, (buf) + L);               \
      gload_lds16(Vb + (size_t)r * NP + (key0) + sc, (buf) + 8192 + L);           \
    }                                                                             \
  }

  char* cur = smem;
  char* nxt = smem + 16384;
  STAGE(cur, 0);
  __syncthreads();   // drains vmcnt(0)

  for (int kc = 0; kc < NP / KVBLK; ++kc) {
    if (kc < NP / KVBLK - 1) STAGE(nxt, (kc + 1) * KVBLK);

    char* Ks = cur;
    char* Vs = cur + 8192;

    // swapped QK^T: s[kt] lane layout = S[key = kt*16 + lk*4 + i][q = lrow]
    f32x4 s[4];
    __builtin_amdgcn_s_setprio(1);
#pragma unroll
    for (int kt = 0; kt < 4; ++kt) {
      const int row = kt * 16 + lrow;
      const int sw = (row & 7) << 4;
      short8 klo = *(const short8*)(Ks + row * 128 + ((lk * 16) ^ sw));
      short8 khi = *(const short8*)(Ks + row * 128 + ((64 + lk * 16) ^ sw));
      f32x4 z = {0.f, 0.f, 0.f, 0.f};
      s[kt] = MFMA_BF16(klo, qf0, z);       // A = K (m=key), B = Q (n=q)
      s[kt] = MFMA_BF16(khi, qf1, s[kt]);
    }
    __builtin_amdgcn_s_setprio(0);

    // P = exp2(S); pack key-pairs in-lane; write P[q=lrow][keys] at identity
    // layout: dword index = key/2 -> byte kt*32 + lk*8 (+4), loop-invariant addr.
#pragma unroll
    for (int kt = 0; kt < 4; ++kt) {
      const float p0 = __builtin_amdgcn_exp2f(s[kt][0]);
      const float p1 = __builtin_amdgcn_exp2f(s[kt][1]);
      const float p2 = __builtin_amdgcn_exp2f(s[kt][2]);
      const float p3 = __builtin_amdgcn_exp2f(s[kt][3]);
      dsa += p0 + p1;
      dsb += p2 + p3;
      uint2 w;
      w.x = pack_bf16x2(p0, p1);
      w.y = pack_bf16x2(p2, p3);
      *(uint2*)(pbuf + lrow * 144 + kt * 32 + lk * 8) = w;
    }

    // PV: A = P[q][key] from pbuf (same-wave DS ordering guarantees visibility),
    // B = V^T frag from swizzled LDS. D[m=q=lk*4+i][n=hd=lrow].
    __builtin_amdgcn_s_setprio(1);
#pragma unroll
    for (int kh = 0; kh < 2; ++kh) {
      short8 a2 = *(const short8*)(pbuf + lrow * 144 + kh * 64 + lk * 16);
#pragma unroll
      for (int hdt = 0; hdt < 4; ++hdt) {
        const int row = hdt * 16 + lrow;
        short8 vf = *(const short8*)(Vs + row * 128 +
                                     ((kh * 64 + lk * 16) ^ ((row & 7) << 4)));
        acc[hdt] = MFMA_BF16(a2, vf, acc[hdt]);
      }
    }
    __builtin_amdgcn_s_setprio(0);

    __syncthreads();   // drains prefetch vmcnt + readers done before overwrite
    char* t = cur; cur = nxt; nxt = t;
  }

  // denominator: lane holds partial for q = lrow over its own lk's keys;
  // combine the 4 lanes (lrow, lk=0..3): lanes lrow + 16*lk -> xor 16, 32.
  float ds = dsa + dsb;
  ds += __shfl_xor(ds, 16);
  ds += __shfl_xor(ds, 32);
  // PV output rows are q = lk*4 + i; fetch that q's denom from lane (lk*4+i) in
  // this 16-group (its lrow == lk*4+i and all lk-groups now agree).
  float rd[4];
#pragma unroll
  for (int i = 0; i < 4; ++i) rd[i] = 1.0f / __shfl(ds, lk * 4 + i, 16);

  const int b = bh / NH, hh = bh % NH;
#pragma unroll
  for (int hdt = 0; hdt < 4; ++hdt) {
#pragma unroll
    for (int i = 0; i < 4; ++i) {
      const int qq = q0 + lk * 4 + i;
      const int col = hh * NHD + hdt * 16 + lrow;
      const float val = acc[hdt][i] * rd[i];
      const size_t o = ((size_t)b * NP + qq) * ND + col;
      wavg_f32[o] = val;
      wavg_bf[o] = __float2bfloat16(val);
    }
  }
#undef STAGE
}

// ---------------- proj GEMM: out[8192][768] = wavg@Wproj + b (fp32 out) ----------------
// grid 192 = 64 mt x 3 nt, XCD swizzled (192 % 8 == 0).

__launch_bounds__(256, 2)
__global__ void k_proj_gemm(const __hip_bfloat16* __restrict__ A,
                            const __hip_bfloat16* __restrict__ BT,
                            const float* __restrict__ bias,
                            float* __restrict__ C) {
  __shared__ char Ls[3 * 24576];
  const int wg = (blockIdx.x & 7) * 24 + (blockIdx.x >> 3);
  const int mt = wg & 63, nt = wg >> 6;
  const int m0 = mt * 128, n0 = nt * 256;
  const int wid = threadIdx.x >> 6, lane = threadIdx.x & 63;
  const int lrow = lane & 15, lk = lane >> 4;

  f32x4 acc[8][4] = {};
  gemm_mainloop(A, BT, m0, n0, Ls, acc);

#pragma unroll
  for (int j = 0; j < 4; ++j) {
    const int n = n0 + wid * 64 + j * 16 + lrow;
    const float bv = bias[n];
#pragma unroll
    for (int i = 0; i < 8; ++i) {
      const int mbase = m0 + i * 16 + lk * 4;
#pragma unroll
      for (int r = 0; r < 4; ++r)
        C[(size_t)(mbase + r) * ND + n] = acc[i][j][r] + bv;
    }
  }
}

// ---------------- launch ----------------

extern "C" void kernel_launch(void* const* d_in, const int* in_sizes, int n_in,
                              void* d_out, int out_size, void* d_ws, size_t ws_size,
                              hipStream_t stream) {
  const float* x      = (const float*)d_in[0];
  const float* w_qkv  = (const float*)d_in[1];
  const float* b_qkv  = (const float*)d_in[2];
  const float* w_proj = (const float*)d_in[3];
  const float* b_proj = (const float*)d_in[4];
  float* out = (float*)d_out;
  float* wavg_out = out + OUT_HALF;

  char* ws = (char*)d_ws;
  // layout (bytes): x_bf16 / wavg_bf16 share (x dead before wavg written)
  __hip_bfloat16* xbf    = (__hip_bfloat16*)(ws);                 // 12,582,912
  __hip_bfloat16* wqkvT  = (__hip_bfloat16*)(ws + 12582912);      //  3,538,944
  __hip_bfloat16* wprojT = (__hip_bfloat16*)(ws + 16121856);      //  1,179,648
  __hip_bfloat16* q_ws   = (__hip_bfloat16*)(ws + 17301504);      // 12,582,912
  __hip_bfloat16* k_ws   = (__hip_bfloat16*)(ws + 29884416);      // 12,582,912
  __hip_bfloat16* v_ws   = (__hip_bfloat16*)(ws + 42467328);      // 12,582,912
  __hip_bfloat16* wavg_bf = xbf;                                  // total 55,050,240 B

  k_cvt_x<<<NTOK * ND / (256 * 8), 256, 0, stream>>>(x, xbf);
  k_cvt_t<<<dim3(ND / 32, N3D / 32), 256, 0, stream>>>(w_qkv, wqkvT, ND, N3D);
  k_cvt_t<<<dim3(ND / 32, ND / 32), 256, 0, stream>>>(w_proj, wprojT, ND, ND);
  k_qkv_gemm<<<(NTOK / 128) * (N3D / 256), 256, 0, stream>>>(xbf, wqkvT, b_qkv,
                                                             q_ws, k_ws, v_ws);
  k_attn<<<dim3(NP / 64, NB * NH), 256, 0, stream>>>(q_ws, k_ws, v_ws, wavg_out, wavg_bf);
  k_proj_gemm<<<(NTOK / 128) * (ND / 256), 256, 0, stream>>>(wavg_bf, wprojT, b_proj, out);
}

// Round 8
// 130.716 us; speedup vs baseline: 1.2229x; 1.2229x over previous
//
#include <hip/hip_runtime.h>
#include <hip/hip_bf16.h>

// Attention block: qkv = x@Wqkv+b; MHA softmax; wavg; out = wavg@Wproj+b.
// B=8, P=1024, D=768, H=12, HD=64. Outputs: [out (8,1024,768), wavg (8,1024,768)] fp32.

typedef __attribute__((ext_vector_type(8))) short short8;
typedef __attribute__((ext_vector_type(4))) float f32x4;

#define MFMA_BF16(a, b, c) __builtin_amdgcn_mfma_f32_16x16x32_bf16((a), (b), (c), 0, 0, 0)

#define NB 8
#define NP 1024
#define ND 768
#define NH 12
#define NHD 64
#define NTOK (NB * NP)         // 8192
#define N3D (3 * ND)           // 2304
#define OUT_HALF (NTOK * ND)   // 6291456
// softmax scale (1/sqrt(64)) * log2(e), folded into Q so P = exp2(S)
#define QSCALE 0.18033688f

__device__ __forceinline__ void gload_lds16(const void* gptr, void* ldsptr) {
  __builtin_amdgcn_global_load_lds(
      (const __attribute__((address_space(1))) unsigned int*)gptr,
      (__attribute__((address_space(3))) unsigned int*)ldsptr, 16, 0, 0);
}

__device__ __forceinline__ unsigned pack_bf16x2(float a, float b) {
  __hip_bfloat162 h = __float22bfloat162_rn(float2{a, b});  // v_cvt_pk_bf16_f32
  return *reinterpret_cast<unsigned*>(&h);                  // a in low 16 bits
}

// GEMM-tile LDS swizzle ([rows][64 B] tiles); involution, XORs byte bits [6:4]
// with [9:7] -> per 16-consecutive-row ds_read_b128 group each bank class is
// hit exactly 2x (free). Verified r6: conflicts 3.5M -> 0.
__device__ __forceinline__ int swz_g(int b) { return b ^ (((b >> 7) & 7) << 4); }

// ---------------- conversion kernels ----------------

__global__ void k_cvt_x(const float* __restrict__ in, __hip_bfloat16* __restrict__ out) {
  int i = (blockIdx.x * 256 + threadIdx.x) * 8;
  float4 a = *(const float4*)(in + i);
  float4 b = *(const float4*)(in + i + 4);
  union { __hip_bfloat16 h[8]; uint4 u; } r;
  r.h[0] = __float2bfloat16(a.x); r.h[1] = __float2bfloat16(a.y);
  r.h[2] = __float2bfloat16(a.z); r.h[3] = __float2bfloat16(a.w);
  r.h[4] = __float2bfloat16(b.x); r.h[5] = __float2bfloat16(b.y);
  r.h[6] = __float2bfloat16(b.z); r.h[7] = __float2bfloat16(b.w);
  *(uint4*)(out + i) = r.u;
}

// in: [K][N] fp32 row-major -> out: [N][K] bf16 row-major (LDS-tiled transpose)
__global__ void k_cvt_t(const float* __restrict__ in, __hip_bfloat16* __restrict__ out,
                        int K, int N) {
  __shared__ float tile[32][33];
  int k0 = blockIdx.x * 32;
  int n0 = blockIdx.y * 32;
  int r = threadIdx.x >> 5;   // 0..7
  int c = threadIdx.x & 31;   // 0..31
#pragma unroll
  for (int i = 0; i < 4; ++i)
    tile[r + 8 * i][c] = in[(size_t)(k0 + r + 8 * i) * N + n0 + c];
  __syncthreads();
#pragma unroll
  for (int i = 0; i < 4; ++i)
    out[(size_t)(n0 + r + 8 * i) * K + k0 + c] = __float2bfloat16(tile[c][r + 8 * i]);
}

// ---------------- shared GEMM mainloop (round-6 verified: 58.7 us qkv) ----------------
// 128x128 tile, BK=32, 4 waves, K=768 fixed. 3 LDS buffers (16 KB each),
// depth-2 prefetch, COUNTED vmcnt(4); vmcnt(0) only on the peeled final
// iteration. swz_g swizzle (rule 21), conflicts measured 0.

__device__ __forceinline__ void gemm_mainloop(const __hip_bfloat16* __restrict__ A,
                                              const __hip_bfloat16* __restrict__ BT,
                                              int m0, int n0, char* Ls,
                                              f32x4 acc[4][4]) {
  const int tid = threadIdx.x;
  const int wid = tid >> 6, lane = tid & 63;
  const int wm = wid >> 1, wn = wid & 1;
  const int lrow = lane & 15, lk = lane >> 4;
  constexpr int K = 768, NKT = K / 32;   // 24 K-steps

  // swizzled, loop-invariant fragment read offsets
  int aoff[4], boff[4];
#pragma unroll
  for (int i = 0; i < 4; ++i) {
    aoff[i] = swz_g((wm * 64 + i * 16 + lrow) * 64 + lk * 16);
    boff[i] = swz_g((wn * 64 + i * 16 + lrow) * 64 + lk * 16);
  }

#define STAGE_G(kt, bi)                                                  \
  {                                                                      \
    const int k0s = (kt) * 32;                                           \
    char* dst = Ls + (bi) * 16384;                                       \
    _Pragma("unroll")                                                    \
    for (int t = 0; t < 2; ++t) {                                        \
      const int L = (tid + t * 256) * 16;  /* linear dest byte */        \
      const int lb = swz_g(L);             /* logical byte for dest L */ \
      const int mr = lb >> 6;              /* tile row (64 B/row) */     \
      const int kk = (lb & 63) >> 1;       /* bf16 col within row */     \
      gload_lds16(A + (size_t)(m0 + mr) * K + k0s + kk,                  \
                  dst + wid * 1024 + t * 4096);                          \
      gload_lds16(BT + (size_t)(n0 + mr) * K + k0s + kk,                 \
                  dst + 8192 + wid * 1024 + t * 4096);                   \
    }                                                                    \
  }

#define COMPUTE_T(kt)                                                          \
  {                                                                            \
    const char* buf = Ls + ((kt) % 3) * 16384;                                 \
    short8 af[4], bf[4];                                                       \
    _Pragma("unroll")                                                          \
    for (int i = 0; i < 4; ++i) {                                              \
      af[i] = *(const short8*)(buf + aoff[i]);                                 \
      bf[i] = *(const short8*)(buf + 8192 + boff[i]);                          \
    }                                                                          \
    _Pragma("unroll")                                                          \
    for (int mi = 0; mi < 4; ++mi)                                             \
      _Pragma("unroll")                                                        \
      for (int ni = 0; ni < 4; ++ni)                                           \
        acc[mi][ni] = MFMA_BF16(af[mi], bf[ni], acc[mi][ni]);                  \
  }

  STAGE_G(0, 0);
  STAGE_G(1, 1);            // 8 loads/wave outstanding

#pragma unroll 3
  for (int kt = 0; kt < NKT - 1; ++kt) {
    asm volatile("s_waitcnt vmcnt(4)" ::: "memory");
    __builtin_amdgcn_s_barrier();
    if (kt + 2 < NKT) STAGE_G(kt + 2, (kt + 2) % 3);
    COMPUTE_T(kt);
  }
  asm volatile("s_waitcnt vmcnt(0)" ::: "memory");
  __builtin_amdgcn_s_barrier();
  COMPUTE_T(NKT - 1);

#undef STAGE_G
#undef COMPUTE_T
}

// ---------------- QKV GEMM: C[8192][2304] = x@Wqkv + b; scatter to q/k/vT ----------------

__launch_bounds__(256)
__global__ void k_qkv_gemm(const __hip_bfloat16* __restrict__ A,
                           const __hip_bfloat16* __restrict__ BT,
                           const float* __restrict__ bias,
                           __hip_bfloat16* __restrict__ q_ws,   // [96][1024][64], pre-scaled
                           __hip_bfloat16* __restrict__ k_ws,   // [96][1024][64]
                           __hip_bfloat16* __restrict__ v_ws) { // [96][64][1024] (V^T)
  __shared__ char Ls[3 * 16384];
  const int mt = blockIdx.x & 63, nt = blockIdx.x >> 6;
  const int m0 = mt * 128, n0 = nt * 128;
  const int wid = threadIdx.x >> 6, lane = threadIdx.x & 63;
  const int wm = wid >> 1, wn = wid & 1;
  const int lrow = lane & 15, lk = lane >> 4;

  f32x4 acc[4][4] = {};
  gemm_mainloop(A, BT, m0, n0, Ls, acc);

  // each 128-wide N-tile lies entirely within q, k, or v (768 % 128 == 0)
  const int which = n0 / ND;
#pragma unroll
  for (int ni = 0; ni < 4; ++ni) {
    const int n = n0 + wn * 64 + ni * 16 + lrow;
    const float bv = bias[n];
    const int hh = (n % ND) >> 6;
    const int hd = n & 63;
#pragma unroll
    for (int mi = 0; mi < 4; ++mi) {
      const int mbase = m0 + wm * 64 + mi * 16 + lk * 4;
#pragma unroll
      for (int i = 0; i < 4; ++i) {
        const int m = mbase + i;
        const float v = acc[mi][ni][i] + bv;
        const int b = m >> 10, p = m & 1023;
        const int bh = b * NH + hh;
        if (which == 0)      q_ws[((size_t)bh * NP + p) * NHD + hd] = __float2bfloat16(v * QSCALE);
        else if (which == 1) k_ws[((size_t)bh * NP + p) * NHD + hd] = __float2bfloat16(v);
        else                 v_ws[((size_t)bh * NHD + hd) * NP + p] = __float2bfloat16(v);
      }
    }
  }
}

// ---------------- attention ----------------
// 1 block = (bh, 128 q-rows), 4 waves x 32 q-rows (two 16-row groups/wave).
// K/V chunks (64 keys) double-buffered in LDS (XOR-swizzled, rule 21);
// K-frags and V-frags loaded once per wave, reused by both q-groups ->
// LDS bytes per q-row ~1.5x lower than the 16-row/wave version.
// Grid = 768 blocks = exact capacity (3/CU); XCD-chunked: each XCD owns 12
// whole heads -> K/V working set 3 MB fits its private L2.
// Swapped QK^T (S^T = mfma(K,Q)): lane holds P for q-row = lrow, 4 keys.

#define KVBLK 64

__launch_bounds__(256)
__global__ void k_attn(const __hip_bfloat16* __restrict__ q_ws,
                       const __hip_bfloat16* __restrict__ k_ws,
                       const __hip_bfloat16* __restrict__ v_ws,  // [bh][64][1024]
                       float* __restrict__ wavg_f32,             // [8][1024][768]
                       __hip_bfloat16* __restrict__ wavg_bf) {
  // [2][K 8KB + V^T 8KB] dbuf + 4 waves x 32 rows x 144 B pbuf = 50 KB
  __shared__ char smem[2 * 16384 + 4 * 4608];
  const int bid = blockIdx.x;                       // 768 = 96 bh x 8 qb
  const int wg = (bid & 7) * 96 + (bid >> 3);       // XCD-chunk: 96 wgs/XCD
  const int bh = wg >> 3, qb = wg & 7;
  const int tid = threadIdx.x;
  const int wid = tid >> 6, lane = tid & 63;
  const int lrow = lane & 15, lk = lane >> 4;
  const int q0 = qb * 128 + wid * 32;
  char* pbuf = smem + 32768 + wid * 4608;           // 32 rows x 144 B

  const __hip_bfloat16* Qb = q_ws + (size_t)bh * NP * NHD;
  const __hip_bfloat16* Kb = k_ws + (size_t)bh * NP * NHD;
  const __hip_bfloat16* Vb = v_ws + (size_t)bh * NHD * NP;

  // Q fragments, two 16-row groups (pre-scaled by QSCALE at QKV epilogue)
  short8 qf[2][2];
#pragma unroll
  for (int g = 0; g < 2; ++g) {
    qf[g][0] = *(const short8*)(Qb + (size_t)(q0 + g * 16 + lrow) * NHD + lk * 8);
    qf[g][1] = *(const short8*)(Qb + (size_t)(q0 + g * 16 + lrow) * NHD + 32 + lk * 8);
  }

  f32x4 acc[2][4] = {};          // [group][hd-tile], 16 q x 16 hd each
  float dsum[2] = {0.f, 0.f};    // per-lane denom partial for q = lrow (group g)

#define STAGE(buf, key0)                                                          \
  {                                                                               \
    _Pragma("unroll")                                                             \
    for (int p = 0; p < 2; ++p) {                                                 \
      const int L = p * 4096 + tid * 16;                                          \
      const int r = L >> 7;                                                       \
      const int cb = L & 127;                                                     \
      const int sc = (cb ^ ((r & 7) << 4)) >> 1;  /* swizzled element col */      \
      gload_lds16(Kb + (size_t)((key0) + r) * NHD + sc, (buf) + L);               \
      gload_lds16(Vb + (size_t)r * NP + (key0) + sc, (buf) + 8192 + L);           \
    }                                                                             \
  }

  char* cur = smem;
  char* nxt = smem + 16384;
  STAGE(cur, 0);
  __syncthreads();   // drains vmcnt(0)

  for (int kc = 0; kc < NP / KVBLK; ++kc) {
    if (kc < NP / KVBLK - 1) STAGE(nxt, (kc + 1) * KVBLK);

    char* Ks = cur;
    char* Vs = cur + 8192;

    // swapped QK^T: s[g][kt] = S[key = kt*16 + lk*4 + i][q = g*16 + lrow]
    // K-frags read once, used by both groups.
    f32x4 s[2][4];
    __builtin_amdgcn_s_setprio(1);
#pragma unroll
    for (int kt = 0; kt < 4; ++kt) {
      const int row = kt * 16 + lrow;
      const int sw = (row & 7) << 4;
      short8 klo = *(const short8*)(Ks + row * 128 + ((lk * 16) ^ sw));
      short8 khi = *(const short8*)(Ks + row * 128 + ((64 + lk * 16) ^ sw));
      f32x4 z = {0.f, 0.f, 0.f, 0.f};
      s[0][kt] = MFMA_BF16(klo, qf[0][0], z);
      s[0][kt] = MFMA_BF16(khi, qf[0][1], s[0][kt]);
      s[1][kt] = MFMA_BF16(klo, qf[1][0], z);
      s[1][kt] = MFMA_BF16(khi, qf[1][1], s[1][kt]);
    }
    __builtin_amdgcn_s_setprio(0);

    // P = exp2(S); pack key pairs in-lane; write P[q][keys] at identity layout
#pragma unroll
    for (int g = 0; g < 2; ++g)
#pragma unroll
      for (int kt = 0; kt < 4; ++kt) {
        const float p0 = __builtin_amdgcn_exp2f(s[g][kt][0]);
        const float p1 = __builtin_amdgcn_exp2f(s[g][kt][1]);
        const float p2 = __builtin_amdgcn_exp2f(s[g][kt][2]);
        const float p3 = __builtin_amdgcn_exp2f(s[g][kt][3]);
        dsum[g] += (p0 + p1) + (p2 + p3);
        uint2 w;
        w.x = pack_bf16x2(p0, p1);
        w.y = pack_bf16x2(p2, p3);
        *(uint2*)(pbuf + (g * 16 + lrow) * 144 + kt * 32 + lk * 8) = w;
      }

    // PV: V-frags read once, used by both groups. D[m=q'][n=hd].
    __builtin_amdgcn_s_setprio(1);
#pragma unroll
    for (int kh = 0; kh < 2; ++kh) {
      short8 a20 = *(const short8*)(pbuf + lrow * 144 + kh * 64 + lk * 16);
      short8 a21 = *(const short8*)(pbuf + (16 + lrow) * 144 + kh * 64 + lk * 16);
#pragma unroll
      for (int hdt = 0; hdt < 4; ++hdt) {
        const int row = hdt * 16 + lrow;
        short8 vf = *(const short8*)(Vs + row * 128 +
                                     ((kh * 64 + lk * 16) ^ ((row & 7) << 4)));
        acc[0][hdt] = MFMA_BF16(a20, vf, acc[0][hdt]);
        acc[1][hdt] = MFMA_BF16(a21, vf, acc[1][hdt]);
      }
    }
    __builtin_amdgcn_s_setprio(0);

    __syncthreads();   // drains prefetch vmcnt + readers done before overwrite
    char* t = cur; cur = nxt; nxt = t;
  }

  const int b = bh / NH, hh = bh % NH;
#pragma unroll
  for (int g = 0; g < 2; ++g) {
    // combine the 4 lk-lanes holding q = lrow partials: xor 16, 32
    float ds = dsum[g];
    ds += __shfl_xor(ds, 16);
    ds += __shfl_xor(ds, 32);
    float rd[4];
#pragma unroll
    for (int i = 0; i < 4; ++i) rd[i] = 1.0f / __shfl(ds, lk * 4 + i, 16);

#pragma unroll
    for (int hdt = 0; hdt < 4; ++hdt) {
#pragma unroll
      for (int i = 0; i < 4; ++i) {
        const int qq = q0 + g * 16 + lk * 4 + i;
        const int col = hh * NHD + hdt * 16 + lrow;
        const float val = acc[g][hdt][i] * rd[i];
        const size_t o = ((size_t)b * NP + qq) * ND + col;
        wavg_f32[o] = val;
        wavg_bf[o] = __float2bfloat16(val);
      }
    }
  }
#undef STAGE
}

// ---------------- proj GEMM: out[8192][768] = wavg@Wproj + b (fp32 out) ----------------

__launch_bounds__(256)
__global__ void k_proj_gemm(const __hip_bfloat16* __restrict__ A,
                            const __hip_bfloat16* __restrict__ BT,
                            const float* __restrict__ bias,
                            float* __restrict__ C) {
  __shared__ char Ls[3 * 16384];
  const int mt = blockIdx.x & 63, nt = blockIdx.x >> 6;
  const int m0 = mt * 128, n0 = nt * 128;
  const int wid = threadIdx.x >> 6, lane = threadIdx.x & 63;
  const int wm = wid >> 1, wn = wid & 1;
  const int lrow = lane & 15, lk = lane >> 4;

  f32x4 acc[4][4] = {};
  gemm_mainloop(A, BT, m0, n0, Ls, acc);

#pragma unroll
  for (int ni = 0; ni < 4; ++ni) {
    const int n = n0 + wn * 64 + ni * 16 + lrow;
    const float bv = bias[n];
#pragma unroll
    for (int mi = 0; mi < 4; ++mi) {
      const int mbase = m0 + wm * 64 + mi * 16 + lk * 4;
#pragma unroll
      for (int i = 0; i < 4; ++i)
        C[(size_t)(mbase + i) * ND + n] = acc[mi][ni][i] + bv;
    }
  }
}

// ---------------- launch ----------------

extern "C" void kernel_launch(void* const* d_in, const int* in_sizes, int n_in,
                              void* d_out, int out_size, void* d_ws, size_t ws_size,
                              hipStream_t stream) {
  const float* x      = (const float*)d_in[0];
  const float* w_qkv  = (const float*)d_in[1];
  const float* b_qkv  = (const float*)d_in[2];
  const float* w_proj = (const float*)d_in[3];
  const float* b_proj = (const float*)d_in[4];
  float* out = (float*)d_out;
  float* wavg_out = out + OUT_HALF;

  char* ws = (char*)d_ws;
  // layout (bytes): x_bf16 / wavg_bf16 share (x dead before wavg written)
  __hip_bfloat16* xbf    = (__hip_bfloat16*)(ws);                 // 12,582,912
  __hip_bfloat16* wqkvT  = (__hip_bfloat16*)(ws + 12582912);      //  3,538,944
  __hip_bfloat16* wprojT = (__hip_bfloat16*)(ws + 16121856);      //  1,179,648
  __hip_bfloat16* q_ws   = (__hip_bfloat16*)(ws + 17301504);      // 12,582,912
  __hip_bfloat16* k_ws   = (__hip_bfloat16*)(ws + 29884416);      // 12,582,912
  __hip_bfloat16* v_ws   = (__hip_bfloat16*)(ws + 42467328);      // 12,582,912
  __hip_bfloat16* wavg_bf = xbf;                                  // total 55,050,240 B

  k_cvt_x<<<NTOK * ND / (256 * 8), 256, 0, stream>>>(x, xbf);
  k_cvt_t<<<dim3(ND / 32, N3D / 32), 256, 0, stream>>>(w_qkv, wqkvT, ND, N3D);
  k_cvt_t<<<dim3(ND / 32, ND / 32), 256, 0, stream>>>(w_proj, wprojT, ND, ND);
  k_qkv_gemm<<<(NTOK / 128) * (N3D / 128), 256, 0, stream>>>(xbf, wqkvT, b_qkv,
                                                             q_ws, k_ws, v_ws);
  k_attn<<<(NP / 128) * (NB * NH), 256, 0, stream>>>(q_ws, k_ws, v_ws, wavg_out, wavg_bf);
  k_proj_gemm<<<(NTOK / 128) * (ND / 128), 256, 0, stream>>>(wavg_bf, wprojT, b_proj, out);
}